// Round 1
// baseline (662.413 us; speedup 1.0000x reference)
//
#include <hip/hip_runtime.h>
#include <hip/hip_bf16.h>

typedef __attribute__((ext_vector_type(8))) short short8;
typedef __attribute__((ext_vector_type(4))) float floatx4;

#define DEVI __device__ __forceinline__

// ---------------- constants ----------------
// B=4, N=512, C_IN=256, RES=7, SR=2, FC_DIM=1024, OUT_CH=94
// M = B*N = 2048 rows, K1 = 256*7*7 = 12544

DEVI unsigned short f2bf(float v) {
  union { __hip_bfloat16 h; unsigned short u; } cv;
  cv.h = __float2bfloat16(v);
  return cv.u;
}

DEVI void gload16(const void* gptr, void* lptr) {
  __builtin_amdgcn_global_load_lds(
      (const __attribute__((address_space(1))) unsigned int*)gptr,
      (__attribute__((address_space(3))) unsigned int*)(unsigned long long)(uintptr_t)lptr,
      16, 0, 0);
}

// ---------------- weight conversion ----------------
__global__ void cvt_bf16_kernel(const float* __restrict__ src,
                                unsigned short* __restrict__ dst, size_t n) {
  size_t i = (size_t)blockIdx.x * blockDim.x + threadIdx.x;
  if (i < n) dst[i] = f2bf(src[i]);
}

// pred_w (94x1024) -> padded (96x1024) bf16, rows 94..95 zero
__global__ void cvt_pad_pred_kernel(const float* __restrict__ src,
                                    unsigned short* __restrict__ dst) {
  int i = blockIdx.x * blockDim.x + threadIdx.x;
  if (i >= 96 * 1024) return;
  int row = i >> 10;
  dst[i] = (row < 94) ? f2bf(src[i]) : (unsigned short)0;
}

// ---------------- ROI align ----------------
// one block per box (2048 blocks). Output X[box][c*49 + py*7 + px] bf16.
__global__ __launch_bounds__(256) void roi_align_kernel(
    const float* __restrict__ p3, const float* __restrict__ p4,
    const float* __restrict__ p5, const float* __restrict__ bbox,
    const int* __restrict__ aid, unsigned short* __restrict__ X) {
  const int box = blockIdx.x;          // 0..2047
  const int b = box >> 9;              // image index (N=512)
  __shared__ int sy0[14], sx0[14];
  __shared__ float sly[14], slx[14];

  const int lvl = aid[box] / 3;        // 0,1,2
  const float* base;
  int H;
  if (lvl == 0)      { base = p3; H = 64; }
  else if (lvl == 1) { base = p4; H = 32; }
  else               { base = p5; H = 16; }
  const float scale = 0.125f / (float)(1 << lvl);

  if (threadIdx.x < 28) {
    int s = threadIdx.x;
    bool isY = s < 14;
    int k = isY ? s : s - 14;
    float lo = bbox[box * 4 + (isY ? 0 : 1)];
    float hi = bbox[box * 4 + (isY ? 2 : 3)];
    float t = lo * scale - 0.5f;
    float cell = (hi - lo) * scale * (1.0f / 7.0f);
    float pos = t + ((float)k + 0.5f) * 0.5f * cell;   // S=14 samples, SR=2
    pos = fminf(fmaxf(pos, 0.0f), (float)(H - 1));
    int i0 = (int)floorf(pos);
    if (i0 > H - 2) i0 = H - 2;        // keep i0+1 valid; fr=1 reproduces clamp
    float fr = pos - (float)i0;
    if (isY) { sy0[k] = i0; sly[k] = fr; }
    else     { sx0[k] = i0; slx[k] = fr; }
  }
  __syncthreads();

  const float* fb = base + (size_t)b * 256 * H * H;
  unsigned short* xo = X + (size_t)box * 12544;

  for (int o = threadIdx.x; o < 12544; o += 256) {
    int c = o / 49, cell = o % 49;
    int py = cell / 7, px = cell % 7;
    const float* fp = fb + (size_t)c * H * H;
    float acc = 0.0f;
#pragma unroll
    for (int sy = 0; sy < 2; ++sy) {
      int si = 2 * py + sy;
      const float* r0 = fp + sy0[si] * H;
      const float* r1 = r0 + H;
      float ly = sly[si];
#pragma unroll
      for (int sx = 0; sx < 2; ++sx) {
        int ti = 2 * px + sx;
        int x0 = sx0[ti];
        float lx = slx[ti];
        float v00 = r0[x0], v01 = r0[x0 + 1];
        float v10 = r1[x0], v11 = r1[x0 + 1];
        float top = v00 + (v01 - v00) * lx;
        float bot = v10 + (v11 - v10) * lx;
        acc += top + (bot - top) * ly;
      }
    }
    xo[o] = f2bf(acc * 0.25f);
  }
}

// ---------------- GEMM: C[M,N] = A[M,K] * Bw[N,K]^T (bf16 in, f32 out) ----------------
template <int BM, int BN, int WAVES_M, int WAVES_N>
__global__ __launch_bounds__(256) void gemm_bt_kernel(
    const unsigned short* __restrict__ A, const unsigned short* __restrict__ Bw,
    float* __restrict__ C, int M, int N, int K) {
  constexpr int BK = 32;
  constexpr int WM = BM / WAVES_M, WN = BN / WAVES_N;
  constexpr int AF = WM / 16, BF = WN / 16;
  constexpr int ASLOT = BM * 4;   // 16B slots per K-step (4 slots of 8 bf16 per row)
  constexpr int BSLOT = BN * 4;
  __shared__ unsigned short As[BM * BK];
  __shared__ unsigned short Bs[BN * BK];

  const int tid = threadIdx.x;
  const int lane = tid & 63, wid = tid >> 6;
  const int wr = wid / WAVES_N, wc = wid % WAVES_N;
  const int tm = blockIdx.x * BM, tn = blockIdx.y * BN;
  const int fr = lane & 15, fg = lane >> 4;

  floatx4 acc[AF][BF];
#pragma unroll
  for (int i = 0; i < AF; ++i)
#pragma unroll
    for (int j = 0; j < BF; ++j)
      acc[i][j] = (floatx4){0.f, 0.f, 0.f, 0.f};

  for (int k0 = 0; k0 < K; k0 += BK) {
#pragma unroll
    for (int s = tid; s < ASLOT; s += 256) {
      int row = s >> 2, kb = (s & 3) << 3;
      gload16(&A[(size_t)(tm + row) * K + k0 + kb], &As[s * 8]);
    }
#pragma unroll
    for (int s = tid; s < BSLOT; s += 256) {
      int row = s >> 2, kb = (s & 3) << 3;
      gload16(&Bw[(size_t)(tn + row) * K + k0 + kb], &Bs[s * 8]);
    }
    __syncthreads();

    short8 af[AF], bfv[BF];
#pragma unroll
    for (int i = 0; i < AF; ++i)
      af[i] = *reinterpret_cast<const short8*>(&As[(wr * WM + i * 16 + fr) * BK + fg * 8]);
#pragma unroll
    for (int j = 0; j < BF; ++j)
      bfv[j] = *reinterpret_cast<const short8*>(&Bs[(wc * WN + j * 16 + fr) * BK + fg * 8]);
#pragma unroll
    for (int i = 0; i < AF; ++i)
#pragma unroll
      for (int j = 0; j < BF; ++j)
        acc[i][j] = __builtin_amdgcn_mfma_f32_16x16x32_bf16(af[i], bfv[j], acc[i][j], 0, 0, 0);
    __syncthreads();
  }

#pragma unroll
  for (int i = 0; i < AF; ++i)
#pragma unroll
    for (int j = 0; j < BF; ++j)
#pragma unroll
      for (int q = 0; q < 4; ++q) {
        int rr = tm + wr * WM + i * 16 + fg * 4 + q;
        int cc = tn + wc * WN + j * 16 + fr;
        C[(size_t)rr * N + cc] = acc[i][j][q];
      }
}

// ---------------- BatchNorm (train mode) ----------------
__global__ void bn_stats_kernel(const float* __restrict__ Y, float* __restrict__ psum,
                                float* __restrict__ psq, int Ncols, int rowsPer) {
  int c = blockIdx.x * blockDim.x + threadIdx.x;
  int r0 = blockIdx.y * rowsPer;
  float s = 0.f, ss = 0.f;
  for (int r = 0; r < rowsPer; ++r) {
    float v = Y[(size_t)(r0 + r) * Ncols + c];
    s += v;
    ss += v * v;
  }
  psum[(size_t)blockIdx.y * Ncols + c] = s;
  psq[(size_t)blockIdx.y * Ncols + c] = ss;
}

__global__ void bn_finalize_kernel(const float* __restrict__ psum, const float* __restrict__ psq,
                                   const float* __restrict__ g, const float* __restrict__ b,
                                   float* __restrict__ scale, float* __restrict__ shift,
                                   int Ncols, int P, float invM) {
  int c = blockIdx.x * blockDim.x + threadIdx.x;
  if (c >= Ncols) return;
  float s = 0.f, ss = 0.f;
  for (int p = 0; p < P; ++p) {
    s += psum[(size_t)p * Ncols + c];
    ss += psq[(size_t)p * Ncols + c];
  }
  float mean = s * invM;
  float var = ss * invM - mean * mean;
  float rstd = rsqrtf(var + 1e-5f);
  float sc = rstd * g[c];
  scale[c] = sc;
  shift[c] = b[c] - mean * sc;
}

__global__ void bn_apply_kernel(const float* __restrict__ Y, const float* __restrict__ scale,
                                const float* __restrict__ shift, unsigned short* __restrict__ X,
                                int NcolsMask, int total) {
  int i = blockIdx.x * blockDim.x + threadIdx.x;
  if (i >= total) return;
  int c = i & NcolsMask;
  float v = Y[i] * scale[c] + shift[c];
  v = fmaxf(v, 0.0f);
  X[i] = f2bf(v);
}

// ---------------- decode ----------------
__global__ void decode_kernel(const float* __restrict__ Y3, const float* __restrict__ pb,
                              const float* __restrict__ anchors, const int* __restrict__ aid,
                              float* __restrict__ out) {
  int i = blockIdx.x * blockDim.x + threadIdx.x;
  if (i >= 2048 * 94) return;
  int bn = i / 94;
  int ch = i - bn * 94;
  float v = Y3[(size_t)bn * 96 + ch] + pb[ch];
  float o = v;
  if (ch >= 4 && ch < 22) {
    int q = ch - 4;
    int d = q % 6;   // within-class: 0,1=yx 2,3=lw 4,5=zh
    if (d < 2) {
      float stride_px = (float)(8 << (aid[bn] / 3));
      o = anchors[(size_t)bn * 4 + d] + v * stride_px;
    } else if (d < 4) {
      float cl = fminf(fmaxf(v, -4.0f), 4.0f);
      o = anchors[(size_t)bn * 4 + d] * expf(cl);
    }
  }
  out[i] = o;
}

// ---------------- launch ----------------
extern "C" void kernel_launch(void* const* d_in, const int* in_sizes, int n_in,
                              void* d_out, int out_size, void* d_ws, size_t ws_size,
                              hipStream_t stream) {
  const float* feat_p3   = (const float*)d_in[0];
  const float* feat_p4   = (const float*)d_in[1];
  const float* feat_p5   = (const float*)d_in[2];
  const float* bbox2d    = (const float*)d_in[3];
  const float* anchors   = (const float*)d_in[4];
  const int*   anchor_id = (const int*)d_in[5];
  const float* fc1_w     = (const float*)d_in[6];
  // d_in[7] fc1_b: cancels through train-mode BN (mean subtraction) — unused
  const float* bn1_g     = (const float*)d_in[8];
  const float* bn1_b     = (const float*)d_in[9];
  const float* fc2_w     = (const float*)d_in[10];
  // d_in[11] fc2_b: cancels — unused
  const float* bn2_g     = (const float*)d_in[12];
  const float* bn2_b     = (const float*)d_in[13];
  const float* pred_w    = (const float*)d_in[14];
  const float* pred_b    = (const float*)d_in[15];
  float* out = (float*)d_out;

  const int M = 2048;          // B*N
  const int K1 = 12544;        // 256*7*7
  const int FC = 1024;

  char* ws = (char*)d_ws;
  auto alloc = [&](size_t bytes) -> char* {
    char* p = ws;
    ws += (bytes + 255) & ~(size_t)255;
    return p;
  };
  unsigned short* W1b = (unsigned short*)alloc((size_t)FC * K1 * 2);
  unsigned short* W2b = (unsigned short*)alloc((size_t)FC * FC * 2);
  unsigned short* W3b = (unsigned short*)alloc((size_t)96 * FC * 2);
  unsigned short* X1  = (unsigned short*)alloc((size_t)M * K1 * 2);
  float*          Y1  = (float*)alloc((size_t)M * FC * 4);
  unsigned short* X2  = (unsigned short*)alloc((size_t)M * FC * 2);
  float*          Y2  = (float*)alloc((size_t)M * FC * 4);
  unsigned short* X3  = (unsigned short*)alloc((size_t)M * FC * 2);
  float*          Y3  = (float*)alloc((size_t)M * 96 * 4);
  float*          ps  = (float*)alloc((size_t)16 * FC * 4);
  float*          pq  = (float*)alloc((size_t)16 * FC * 4);
  float*          sc1 = (float*)alloc((size_t)FC * 4);
  float*          sh1 = (float*)alloc((size_t)FC * 4);
  float*          sc2 = (float*)alloc((size_t)FC * 4);
  float*          sh2 = (float*)alloc((size_t)FC * 4);

  // weight conversions (must redo each call — no cross-call state allowed)
  {
    size_t n = (size_t)FC * K1;
    cvt_bf16_kernel<<<(unsigned)((n + 255) / 256), 256, 0, stream>>>(fc1_w, W1b, n);
  }
  {
    size_t n = (size_t)FC * FC;
    cvt_bf16_kernel<<<(unsigned)((n + 255) / 256), 256, 0, stream>>>(fc2_w, W2b, n);
  }
  cvt_pad_pred_kernel<<<(96 * 1024) / 256, 256, 0, stream>>>(pred_w, W3b);

  // ROI align -> X1 (2048 x 12544) bf16
  roi_align_kernel<<<2048, 256, 0, stream>>>(feat_p3, feat_p4, feat_p5, bbox2d, anchor_id, X1);

  // fc1: X1 (2048x12544) @ W1^T -> Y1 (2048x1024)
  gemm_bt_kernel<128, 64, 2, 2><<<dim3(M / 128, FC / 64), 256, 0, stream>>>(X1, W1b, Y1, M, FC, K1);

  // BN1 + ReLU -> X2 bf16
  bn_stats_kernel<<<dim3(FC / 256, 16), 256, 0, stream>>>(Y1, ps, pq, FC, M / 16);
  bn_finalize_kernel<<<FC / 256, 256, 0, stream>>>(ps, pq, bn1_g, bn1_b, sc1, sh1, FC, 16, 1.0f / M);
  bn_apply_kernel<<<(M * FC) / 256, 256, 0, stream>>>(Y1, sc1, sh1, X2, FC - 1, M * FC);

  // fc2
  gemm_bt_kernel<128, 64, 2, 2><<<dim3(M / 128, FC / 64), 256, 0, stream>>>(X2, W2b, Y2, M, FC, FC);

  // BN2 + ReLU -> X3 bf16
  bn_stats_kernel<<<dim3(FC / 256, 16), 256, 0, stream>>>(Y2, ps, pq, FC, M / 16);
  bn_finalize_kernel<<<FC / 256, 256, 0, stream>>>(ps, pq, bn2_g, bn2_b, sc2, sh2, FC, 16, 1.0f / M);
  bn_apply_kernel<<<(M * FC) / 256, 256, 0, stream>>>(Y2, sc2, sh2, X3, FC - 1, M * FC);

  // pred head: X3 @ W3p^T -> Y3 (2048 x 96, first 94 valid)
  gemm_bt_kernel<64, 96, 2, 2><<<dim3(M / 64, 1), 256, 0, stream>>>(X3, W3b, Y3, M, 96, FC);

  // decode -> out (2048 x 94)
  decode_kernel<<<(2048 * 94 + 255) / 256, 256, 0, stream>>>(Y3, pred_b, anchors, anchor_id, out);
}

// Round 2
// 439.394 us; speedup vs baseline: 1.5076x; 1.5076x over previous
//
#include <hip/hip_runtime.h>
#include <hip/hip_bf16.h>

typedef __attribute__((ext_vector_type(8))) short short8;
typedef __attribute__((ext_vector_type(4))) float floatx4;

#define DEVI __device__ __forceinline__

// ---------------- constants ----------------
// B=4, N=512, C_IN=256, RES=7, SR=2, FC_DIM=1024, OUT_CH=94
// M = B*N = 2048 rows, K1 = 256*7*7 = 12544

DEVI unsigned short f2bf(float v) {
  union { __hip_bfloat16 h; unsigned short u; } cv;
  cv.h = __float2bfloat16(v);
  return cv.u;
}

DEVI void gload16(const void* gptr, void* lptr) {
  __builtin_amdgcn_global_load_lds(
      (const __attribute__((address_space(1))) unsigned int*)gptr,
      (__attribute__((address_space(3))) unsigned int*)(unsigned long long)(uintptr_t)lptr,
      16, 0, 0);
}

// ---------------- weight conversion ----------------
__global__ void cvt_bf16_kernel(const float* __restrict__ src,
                                unsigned short* __restrict__ dst, size_t n) {
  size_t i = (size_t)blockIdx.x * blockDim.x + threadIdx.x;
  if (i < n) dst[i] = f2bf(src[i]);
}

// pred_w (94x1024) -> padded (96x1024) bf16, rows 94..95 zero
__global__ void cvt_pad_pred_kernel(const float* __restrict__ src,
                                    unsigned short* __restrict__ dst) {
  int i = blockIdx.x * blockDim.x + threadIdx.x;
  if (i >= 96 * 1024) return;
  int row = i >> 10;
  dst[i] = (row < 94) ? f2bf(src[i]) : (unsigned short)0;
}

// ---------------- ROI align v2: LDS-staged ----------------
// One block per box. The 14x14 sample grid spans <=16x16 texels per channel
// (span = 6.5*cell <= 13.93px). Stage 32 channels' 16x16 patches into LDS
// (channel stride 273 floats -> channel offsets distinct banks mod 32),
// then compute 49 cells/channel from LDS.
__global__ __launch_bounds__(256) void roi_align_v2(
    const float* __restrict__ p3, const float* __restrict__ p4,
    const float* __restrict__ p5, const float* __restrict__ bbox,
    const int* __restrict__ aid, unsigned short* __restrict__ X) {
  const int box = blockIdx.x;          // 0..2047
  const int b = box >> 9;              // image index (N=512)
  const int tid = threadIdx.x;
  __shared__ int sy0[14], sx0[14];
  __shared__ float sly[14], slx[14];
  __shared__ float st[32 * 273];       // 34.9 KB

  const int lvl = aid[box] / 3;        // 0,1,2
  const float* base;
  int H;
  if (lvl == 0)      { base = p3; H = 64; }
  else if (lvl == 1) { base = p4; H = 32; }
  else               { base = p5; H = 16; }
  const float scale = 0.125f / (float)(1 << lvl);

  if (tid < 28) {
    int s = tid;
    bool isY = s < 14;
    int k = isY ? s : s - 14;
    float lo = bbox[box * 4 + (isY ? 0 : 1)];
    float hi = bbox[box * 4 + (isY ? 2 : 3)];
    float t = lo * scale - 0.5f;
    float cell = (hi - lo) * scale * (1.0f / 7.0f);
    float pos = t + ((float)k + 0.5f) * 0.5f * cell;   // S=14 samples, SR=2
    pos = fminf(fmaxf(pos, 0.0f), (float)(H - 1));
    int i0 = (int)floorf(pos);
    if (i0 > H - 2) i0 = H - 2;        // keep i0+1 valid; fr=1 reproduces clamp
    float fr = pos - (float)i0;
    if (isY) { sy0[k] = i0; sly[k] = fr; }
    else     { sx0[k] = i0; slx[k] = fr; }
  }
  __syncthreads();

  const int ry0 = sy0[0], rx0 = sx0[0];   // monotone grid -> these are minima
  const int HH = H * H;
  const float* fb = base + (size_t)b * 256 * HH;

  // staging map: thread -> (row = tid>>4, col = tid&15) of the 16x16 patch
  const int gy = min(ry0 + (tid >> 4), H - 1);
  const int gx = min(rx0 + (tid & 15), H - 1);
  const float* srcp = fb + gy * H + gx;
  float* stw = &st[(tid >> 4) * 17 + (tid & 15)];

  // compute map: 8 threads per channel
  const int cl = tid >> 3;             // 0..31 local channel
  const int c0 = tid & 7;
  const float* stc = &st[cl * 273];

  for (int g = 0; g < 8; ++g) {
    const float* s0 = srcp + (size_t)(g * 32) * HH;
#pragma unroll
    for (int k = 0; k < 32; ++k)
      stw[k * 273] = s0[(size_t)k * HH];
    __syncthreads();

    unsigned short* xoc = X + (size_t)box * 12544 + (size_t)(g * 32 + cl) * 49;
    for (int cell = c0; cell < 49; cell += 8) {
      int py = (cell * 37) >> 8;       // == cell/7 for 0..55
      int px = cell - py * 7;
      float acc = 0.0f;
#pragma unroll
      for (int sy = 0; sy < 2; ++sy) {
        int si = 2 * py + sy;
        float ly = sly[si];
        const float* r0 = stc + (sy0[si] - ry0) * 17;
        const float* r1 = r0 + 17;
#pragma unroll
        for (int sx = 0; sx < 2; ++sx) {
          int ti = 2 * px + sx;
          float lx = slx[ti];
          int xl = sx0[ti] - rx0;
          float v00 = r0[xl], v01 = r0[xl + 1];
          float v10 = r1[xl], v11 = r1[xl + 1];
          float top = v00 + (v01 - v00) * lx;
          float bot = v10 + (v11 - v10) * lx;
          acc += top + (bot - top) * ly;
        }
      }
      xoc[cell] = f2bf(acc * 0.25f);
    }
    __syncthreads();
  }
}

// ---------------- GEMM: C[M,N] = A[M,K] * Bw[N,K]^T (bf16 in, f32 out) ----------------
template <int BM, int BN, int WAVES_M, int WAVES_N, int KSPLIT>
__global__ __launch_bounds__(256) void gemm_bt_kernel(
    const unsigned short* __restrict__ A, const unsigned short* __restrict__ Bw,
    float* __restrict__ C, int M, int N, int K) {
  constexpr int BK = 32;
  constexpr int WM = BM / WAVES_M, WN = BN / WAVES_N;
  constexpr int AF = WM / 16, BF = WN / 16;
  constexpr int ASLOT = BM * 4;   // 16B slots per K-step (4 slots of 8 bf16 per row)
  constexpr int BSLOT = BN * 4;
  __shared__ unsigned short As[BM * BK];
  __shared__ unsigned short Bs[BN * BK];

  const int tid = threadIdx.x;
  const int lane = tid & 63, wid = tid >> 6;
  const int wr = wid / WAVES_N, wc = wid % WAVES_N;
  const int tm = blockIdx.x * BM, tn = blockIdx.y * BN;
  const int fr = lane & 15, fg = lane >> 4;

  const int kLen = K / KSPLIT;
  const int kBeg = blockIdx.z * kLen;
  float* Cz = C + (size_t)blockIdx.z * M * N;

  floatx4 acc[AF][BF];
#pragma unroll
  for (int i = 0; i < AF; ++i)
#pragma unroll
    for (int j = 0; j < BF; ++j)
      acc[i][j] = (floatx4){0.f, 0.f, 0.f, 0.f};

  for (int k0 = kBeg; k0 < kBeg + kLen; k0 += BK) {
#pragma unroll
    for (int s = tid; s < ASLOT; s += 256) {
      int row = s >> 2, kb = (s & 3) << 3;
      gload16(&A[(size_t)(tm + row) * K + k0 + kb], &As[s * 8]);
    }
#pragma unroll
    for (int s = tid; s < BSLOT; s += 256) {
      int row = s >> 2, kb = (s & 3) << 3;
      gload16(&Bw[(size_t)(tn + row) * K + k0 + kb], &Bs[s * 8]);
    }
    __syncthreads();

    short8 af[AF], bfv[BF];
#pragma unroll
    for (int i = 0; i < AF; ++i)
      af[i] = *reinterpret_cast<const short8*>(&As[(wr * WM + i * 16 + fr) * BK + fg * 8]);
#pragma unroll
    for (int j = 0; j < BF; ++j)
      bfv[j] = *reinterpret_cast<const short8*>(&Bs[(wc * WN + j * 16 + fr) * BK + fg * 8]);
#pragma unroll
    for (int i = 0; i < AF; ++i)
#pragma unroll
      for (int j = 0; j < BF; ++j)
        acc[i][j] = __builtin_amdgcn_mfma_f32_16x16x32_bf16(af[i], bfv[j], acc[i][j], 0, 0, 0);
    __syncthreads();
  }

#pragma unroll
  for (int i = 0; i < AF; ++i)
#pragma unroll
    for (int j = 0; j < BF; ++j)
#pragma unroll
      for (int q = 0; q < 4; ++q) {
        int rr = tm + wr * WM + i * 16 + fg * 4 + q;
        int cc = tn + wc * WN + j * 16 + fr;
        Cz[(size_t)rr * N + cc] = acc[i][j][q];
      }
}

// ---------------- BatchNorm (train mode) ----------------
__global__ void bn_stats_kernel(const float* __restrict__ Y, float* __restrict__ psum,
                                float* __restrict__ psq, int Ncols, int rowsPer) {
  int c = blockIdx.x * blockDim.x + threadIdx.x;
  int r0 = blockIdx.y * rowsPer;
  float s = 0.f, ss = 0.f;
  for (int r = 0; r < rowsPer; ++r) {
    float v = Y[(size_t)(r0 + r) * Ncols + c];
    s += v;
    ss += v * v;
  }
  psum[(size_t)blockIdx.y * Ncols + c] = s;
  psq[(size_t)blockIdx.y * Ncols + c] = ss;
}

__global__ void bn_finalize_kernel(const float* __restrict__ psum, const float* __restrict__ psq,
                                   const float* __restrict__ g, const float* __restrict__ b,
                                   float* __restrict__ scale, float* __restrict__ shift,
                                   int Ncols, int P, float invM) {
  int c = blockIdx.x * blockDim.x + threadIdx.x;
  if (c >= Ncols) return;
  float s = 0.f, ss = 0.f;
  for (int p = 0; p < P; ++p) {
    s += psum[(size_t)p * Ncols + c];
    ss += psq[(size_t)p * Ncols + c];
  }
  float mean = s * invM;
  float var = ss * invM - mean * mean;
  float rstd = rsqrtf(var + 1e-5f);
  float sc = rstd * g[c];
  scale[c] = sc;
  shift[c] = b[c] - mean * sc;
}

__global__ void bn_apply_kernel(const float* __restrict__ Y, const float* __restrict__ scale,
                                const float* __restrict__ shift, unsigned short* __restrict__ X,
                                int NcolsMask, int total) {
  int i = blockIdx.x * blockDim.x + threadIdx.x;
  if (i >= total) return;
  int c = i & NcolsMask;
  float v = Y[i] * scale[c] + shift[c];
  v = fmaxf(v, 0.0f);
  X[i] = f2bf(v);
}

// ---------------- decode ----------------
// Y3 holds KSPLIT=4 partials of (2048 x 96)
__global__ void decode_kernel(const float* __restrict__ Y3, const float* __restrict__ pb,
                              const float* __restrict__ anchors, const int* __restrict__ aid,
                              float* __restrict__ out) {
  int i = blockIdx.x * blockDim.x + threadIdx.x;
  if (i >= 2048 * 94) return;
  int bn = i / 94;
  int ch = i - bn * 94;
  size_t idx = (size_t)bn * 96 + ch;
  float v = Y3[idx] + Y3[idx + 2048 * 96] + Y3[idx + 2 * 2048 * 96] + Y3[idx + 3 * 2048 * 96];
  v += pb[ch];
  float o = v;
  if (ch >= 4 && ch < 22) {
    int q = ch - 4;
    int d = q % 6;   // within-class: 0,1=yx 2,3=lw 4,5=zh
    if (d < 2) {
      float stride_px = (float)(8 << (aid[bn] / 3));
      o = anchors[(size_t)bn * 4 + d] + v * stride_px;
    } else if (d < 4) {
      float cl = fminf(fmaxf(v, -4.0f), 4.0f);
      o = anchors[(size_t)bn * 4 + d] * expf(cl);
    }
  }
  out[i] = o;
}

// ---------------- launch ----------------
extern "C" void kernel_launch(void* const* d_in, const int* in_sizes, int n_in,
                              void* d_out, int out_size, void* d_ws, size_t ws_size,
                              hipStream_t stream) {
  const float* feat_p3   = (const float*)d_in[0];
  const float* feat_p4   = (const float*)d_in[1];
  const float* feat_p5   = (const float*)d_in[2];
  const float* bbox2d    = (const float*)d_in[3];
  const float* anchors   = (const float*)d_in[4];
  const int*   anchor_id = (const int*)d_in[5];
  const float* fc1_w     = (const float*)d_in[6];
  // d_in[7] fc1_b: cancels through train-mode BN (mean subtraction) — unused
  const float* bn1_g     = (const float*)d_in[8];
  const float* bn1_b     = (const float*)d_in[9];
  const float* fc2_w     = (const float*)d_in[10];
  // d_in[11] fc2_b: cancels — unused
  const float* bn2_g     = (const float*)d_in[12];
  const float* bn2_b     = (const float*)d_in[13];
  const float* pred_w    = (const float*)d_in[14];
  const float* pred_b    = (const float*)d_in[15];
  float* out = (float*)d_out;

  const int M = 2048;          // B*N
  const int K1 = 12544;        // 256*7*7
  const int FC = 1024;

  char* ws = (char*)d_ws;
  auto alloc = [&](size_t bytes) -> char* {
    char* p = ws;
    ws += (bytes + 255) & ~(size_t)255;
    return p;
  };
  unsigned short* W1b = (unsigned short*)alloc((size_t)FC * K1 * 2);
  unsigned short* W2b = (unsigned short*)alloc((size_t)FC * FC * 2);
  unsigned short* W3b = (unsigned short*)alloc((size_t)96 * FC * 2);
  unsigned short* X1  = (unsigned short*)alloc((size_t)M * K1 * 2);
  float*          Y1  = (float*)alloc((size_t)M * FC * 4);
  unsigned short* X2  = (unsigned short*)alloc((size_t)M * FC * 2);
  float*          Y2  = (float*)alloc((size_t)M * FC * 4);
  unsigned short* X3  = (unsigned short*)alloc((size_t)M * FC * 2);
  float*          Y3  = (float*)alloc((size_t)4 * M * 96 * 4);
  float*          ps  = (float*)alloc((size_t)16 * FC * 4);
  float*          pq  = (float*)alloc((size_t)16 * FC * 4);
  float*          sc1 = (float*)alloc((size_t)FC * 4);
  float*          sh1 = (float*)alloc((size_t)FC * 4);
  float*          sc2 = (float*)alloc((size_t)FC * 4);
  float*          sh2 = (float*)alloc((size_t)FC * 4);

  // weight conversions (must redo each call — no cross-call state allowed)
  {
    size_t n = (size_t)FC * K1;
    cvt_bf16_kernel<<<(unsigned)((n + 255) / 256), 256, 0, stream>>>(fc1_w, W1b, n);
  }
  {
    size_t n = (size_t)FC * FC;
    cvt_bf16_kernel<<<(unsigned)((n + 255) / 256), 256, 0, stream>>>(fc2_w, W2b, n);
  }
  cvt_pad_pred_kernel<<<(96 * 1024) / 256, 256, 0, stream>>>(pred_w, W3b);

  // ROI align -> X1 (2048 x 12544) bf16
  roi_align_v2<<<2048, 256, 0, stream>>>(feat_p3, feat_p4, feat_p5, bbox2d, anchor_id, X1);

  // fc1: X1 (2048x12544) @ W1^T -> Y1 (2048x1024)
  gemm_bt_kernel<128, 64, 2, 2, 1><<<dim3(M / 128, FC / 64), 256, 0, stream>>>(X1, W1b, Y1, M, FC, K1);

  // BN1 + ReLU -> X2 bf16
  bn_stats_kernel<<<dim3(FC / 256, 16), 256, 0, stream>>>(Y1, ps, pq, FC, M / 16);
  bn_finalize_kernel<<<FC / 256, 256, 0, stream>>>(ps, pq, bn1_g, bn1_b, sc1, sh1, FC, 16, 1.0f / M);
  bn_apply_kernel<<<(M * FC) / 256, 256, 0, stream>>>(Y1, sc1, sh1, X2, FC - 1, M * FC);

  // fc2
  gemm_bt_kernel<128, 64, 2, 2, 1><<<dim3(M / 128, FC / 64), 256, 0, stream>>>(X2, W2b, Y2, M, FC, FC);

  // BN2 + ReLU -> X3 bf16
  bn_stats_kernel<<<dim3(FC / 256, 16), 256, 0, stream>>>(Y2, ps, pq, FC, M / 16);
  bn_finalize_kernel<<<FC / 256, 256, 0, stream>>>(ps, pq, bn2_g, bn2_b, sc2, sh2, FC, 16, 1.0f / M);
  bn_apply_kernel<<<(M * FC) / 256, 256, 0, stream>>>(Y2, sc2, sh2, X3, FC - 1, M * FC);

  // pred head: X3 @ W3p^T -> Y3 (split-K=4 partials of 2048 x 96)
  gemm_bt_kernel<64, 96, 2, 2, 4><<<dim3(M / 64, 1, 4), 256, 0, stream>>>(X3, W3b, Y3, M, 96, FC);

  // decode -> out (2048 x 94)
  decode_kernel<<<(2048 * 94 + 255) / 256, 256, 0, stream>>>(Y3, pred_b, anchors, anchor_id, out);
}

// Round 3
// 376.862 us; speedup vs baseline: 1.7577x; 1.1659x over previous
//
#include <hip/hip_runtime.h>
#include <hip/hip_bf16.h>

typedef __attribute__((ext_vector_type(8))) short short8;
typedef __attribute__((ext_vector_type(4))) float floatx4;

#define DEVI __device__ __forceinline__

// ---------------- constants ----------------
// B=4, N=512, C_IN=256, RES=7, SR=2, FC_DIM=1024, OUT_CH=94
// M = B*N = 2048 rows, K1 = 256*7*7 = 12544

DEVI unsigned short f2bf(float v) {
  union { __hip_bfloat16 h; unsigned short u; } cv;
  cv.h = __float2bfloat16(v);
  return cv.u;
}

DEVI void gload16(const void* gptr, void* lptr) {
  __builtin_amdgcn_global_load_lds(
      (const __attribute__((address_space(1))) unsigned int*)gptr,
      (__attribute__((address_space(3))) unsigned int*)(unsigned long long)(uintptr_t)lptr,
      16, 0, 0);
}

// ---------------- weight conversion ----------------
__global__ void cvt_bf16_kernel(const float* __restrict__ src,
                                unsigned short* __restrict__ dst, size_t n) {
  size_t i = (size_t)blockIdx.x * blockDim.x + threadIdx.x;
  if (i < n) dst[i] = f2bf(src[i]);
}

// pred_w (94x1024) -> padded (96x1024) bf16, rows 94..95 zero
__global__ void cvt_pad_pred_kernel(const float* __restrict__ src,
                                    unsigned short* __restrict__ dst) {
  int i = blockIdx.x * blockDim.x + threadIdx.x;
  if (i >= 96 * 1024) return;
  int row = i >> 10;
  dst[i] = (row < 94) ? f2bf(src[i]) : (unsigned short)0;
}

// ---------------- ROI align v2: LDS-staged ----------------
__global__ __launch_bounds__(256) void roi_align_v2(
    const float* __restrict__ p3, const float* __restrict__ p4,
    const float* __restrict__ p5, const float* __restrict__ bbox,
    const int* __restrict__ aid, unsigned short* __restrict__ X) {
  const int box = blockIdx.x;          // 0..2047
  const int b = box >> 9;              // image index (N=512)
  const int tid = threadIdx.x;
  __shared__ int sy0[14], sx0[14];
  __shared__ float sly[14], slx[14];
  __shared__ float st[32 * 273];       // 34.9 KB

  const int lvl = aid[box] / 3;        // 0,1,2
  const float* base;
  int H;
  if (lvl == 0)      { base = p3; H = 64; }
  else if (lvl == 1) { base = p4; H = 32; }
  else               { base = p5; H = 16; }
  const float scale = 0.125f / (float)(1 << lvl);

  if (tid < 28) {
    int s = tid;
    bool isY = s < 14;
    int k = isY ? s : s - 14;
    float lo = bbox[box * 4 + (isY ? 0 : 1)];
    float hi = bbox[box * 4 + (isY ? 2 : 3)];
    float t = lo * scale - 0.5f;
    float cell = (hi - lo) * scale * (1.0f / 7.0f);
    float pos = t + ((float)k + 0.5f) * 0.5f * cell;   // S=14 samples, SR=2
    pos = fminf(fmaxf(pos, 0.0f), (float)(H - 1));
    int i0 = (int)floorf(pos);
    if (i0 > H - 2) i0 = H - 2;        // keep i0+1 valid; fr=1 reproduces clamp
    float fr = pos - (float)i0;
    if (isY) { sy0[k] = i0; sly[k] = fr; }
    else     { sx0[k] = i0; slx[k] = fr; }
  }
  __syncthreads();

  const int ry0 = sy0[0], rx0 = sx0[0];   // monotone grid -> these are minima
  const int HH = H * H;
  const float* fb = base + (size_t)b * 256 * HH;

  const int gy = min(ry0 + (tid >> 4), H - 1);
  const int gx = min(rx0 + (tid & 15), H - 1);
  const float* srcp = fb + gy * H + gx;
  float* stw = &st[(tid >> 4) * 17 + (tid & 15)];

  const int cl = tid >> 3;             // 0..31 local channel
  const int c0 = tid & 7;
  const float* stc = &st[cl * 273];

  for (int g = 0; g < 8; ++g) {
    const float* s0 = srcp + (size_t)(g * 32) * HH;
#pragma unroll
    for (int k = 0; k < 32; ++k)
      stw[k * 273] = s0[(size_t)k * HH];
    __syncthreads();

    unsigned short* xoc = X + (size_t)box * 12544 + (size_t)(g * 32 + cl) * 49;
    for (int cell = c0; cell < 49; cell += 8) {
      int py = (cell * 37) >> 8;       // == cell/7 for 0..55
      int px = cell - py * 7;
      float acc = 0.0f;
#pragma unroll
      for (int sy = 0; sy < 2; ++sy) {
        int si = 2 * py + sy;
        float ly = sly[si];
        const float* r0 = stc + (sy0[si] - ry0) * 17;
        const float* r1 = r0 + 17;
#pragma unroll
        for (int sx = 0; sx < 2; ++sx) {
          int ti = 2 * px + sx;
          float lx = slx[ti];
          int xl = sx0[ti] - rx0;
          float v00 = r0[xl], v01 = r0[xl + 1];
          float v10 = r1[xl], v11 = r1[xl + 1];
          float top = v00 + (v01 - v00) * lx;
          float bot = v10 + (v11 - v10) * lx;
          acc += top + (bot - top) * ly;
        }
      }
      xoc[cell] = f2bf(acc * 0.25f);
    }
    __syncthreads();
  }
}

// ---------------- GEMM v2: 128x128 tile, BK=64, T2 XOR-swizzle, split-K ----------------
// C[z][M,N] partial = A[M, kchunk] * Bw[N, kchunk]^T
// LDS rows are 64 bf16 = 8 x 16B slots; slot s of row r holds global slot s^(r&7)
// (linear LDS dest for global_load_lds, inverse-swizzled global source, swizzled read).
template <int KSPLIT>
__global__ __launch_bounds__(256) void gemm_bt_swz(
    const unsigned short* __restrict__ A, const unsigned short* __restrict__ Bw,
    float* __restrict__ C, int M, int N, int K) {
  constexpr int BM = 128, BN = 128, BK = 64;
  __shared__ unsigned short As[BM * BK];   // 16 KB
  __shared__ unsigned short Bs[BN * BK];   // 16 KB

  const int tid = threadIdx.x;
  const int lane = tid & 63, wid = tid >> 6;
  const int wr = wid >> 1, wc = wid & 1;    // 2x2 waves, 64x64 each
  const int tm = blockIdx.x * BM, tn = blockIdx.y * BN;
  const int fr = lane & 15, fg = lane >> 4;

  const int kLen = K / KSPLIT;
  const int kTiles = kLen / BK;
  const int kBeg = blockIdx.z * kLen;
  float* Cz = C + (size_t)blockIdx.z * M * N;

  floatx4 acc[4][4];
#pragma unroll
  for (int i = 0; i < 4; ++i)
#pragma unroll
    for (int j = 0; j < 4; ++j)
      acc[i][j] = (floatx4){0.f, 0.f, 0.f, 0.f};

  for (int t = 0; t < kTiles; ++t) {
    const int k0 = kBeg + t * BK;
#pragma unroll
    for (int s = tid; s < BM * 8; s += 256) {
      int row = s >> 3, sl = s & 7;
      int slg = sl ^ (row & 7);
      gload16(&A[(size_t)(tm + row) * K + k0 + slg * 8], &As[s * 8]);
    }
#pragma unroll
    for (int s = tid; s < BN * 8; s += 256) {
      int row = s >> 3, sl = s & 7;
      int slg = sl ^ (row & 7);
      gload16(&Bw[(size_t)(tn + row) * K + k0 + slg * 8], &Bs[s * 8]);
    }
    __syncthreads();

#pragma unroll
    for (int kk = 0; kk < 2; ++kk) {
      short8 af[4], bf[4];
#pragma unroll
      for (int i = 0; i < 4; ++i) {
        int row = wr * 64 + i * 16 + fr;
        int sl = (kk * 4 + fg) ^ (row & 7);
        af[i] = *reinterpret_cast<const short8*>(&As[(row * 8 + sl) * 8]);
      }
#pragma unroll
      for (int j = 0; j < 4; ++j) {
        int row = wc * 64 + j * 16 + fr;
        int sl = (kk * 4 + fg) ^ (row & 7);
        bf[j] = *reinterpret_cast<const short8*>(&Bs[(row * 8 + sl) * 8]);
      }
#pragma unroll
      for (int i = 0; i < 4; ++i)
#pragma unroll
        for (int j = 0; j < 4; ++j)
          acc[i][j] = __builtin_amdgcn_mfma_f32_16x16x32_bf16(af[i], bf[j], acc[i][j], 0, 0, 0);
    }
    __syncthreads();
  }

#pragma unroll
  for (int i = 0; i < 4; ++i)
#pragma unroll
    for (int j = 0; j < 4; ++j)
#pragma unroll
      for (int q = 0; q < 4; ++q) {
        int rr = tm + wr * 64 + i * 16 + fg * 4 + q;
        int cc = tn + wc * 64 + j * 16 + fr;
        Cz[(size_t)rr * N + cc] = acc[i][j][q];
      }
}

// ---------------- old GEMM (pred head only) ----------------
template <int BM, int BN, int WAVES_M, int WAVES_N, int KSPLIT>
__global__ __launch_bounds__(256) void gemm_bt_kernel(
    const unsigned short* __restrict__ A, const unsigned short* __restrict__ Bw,
    float* __restrict__ C, int M, int N, int K) {
  constexpr int BK = 32;
  constexpr int WM = BM / WAVES_M, WN = BN / WAVES_N;
  constexpr int AF = WM / 16, BF = WN / 16;
  constexpr int ASLOT = BM * 4;
  constexpr int BSLOT = BN * 4;
  __shared__ unsigned short As[BM * BK];
  __shared__ unsigned short Bs[BN * BK];

  const int tid = threadIdx.x;
  const int lane = tid & 63, wid = tid >> 6;
  const int wr = wid / WAVES_N, wc = wid % WAVES_N;
  const int tm = blockIdx.x * BM, tn = blockIdx.y * BN;
  const int fr = lane & 15, fg = lane >> 4;

  const int kLen = K / KSPLIT;
  const int kBeg = blockIdx.z * kLen;
  float* Cz = C + (size_t)blockIdx.z * M * N;

  floatx4 acc[AF][BF];
#pragma unroll
  for (int i = 0; i < AF; ++i)
#pragma unroll
    for (int j = 0; j < BF; ++j)
      acc[i][j] = (floatx4){0.f, 0.f, 0.f, 0.f};

  for (int k0 = kBeg; k0 < kBeg + kLen; k0 += BK) {
#pragma unroll
    for (int s = tid; s < ASLOT; s += 256) {
      int row = s >> 2, kb = (s & 3) << 3;
      gload16(&A[(size_t)(tm + row) * K + k0 + kb], &As[s * 8]);
    }
#pragma unroll
    for (int s = tid; s < BSLOT; s += 256) {
      int row = s >> 2, kb = (s & 3) << 3;
      gload16(&Bw[(size_t)(tn + row) * K + k0 + kb], &Bs[s * 8]);
    }
    __syncthreads();

    short8 af[AF], bfv[BF];
#pragma unroll
    for (int i = 0; i < AF; ++i)
      af[i] = *reinterpret_cast<const short8*>(&As[(wr * WM + i * 16 + fr) * BK + fg * 8]);
#pragma unroll
    for (int j = 0; j < BF; ++j)
      bfv[j] = *reinterpret_cast<const short8*>(&Bs[(wc * WN + j * 16 + fr) * BK + fg * 8]);
#pragma unroll
    for (int i = 0; i < AF; ++i)
#pragma unroll
      for (int j = 0; j < BF; ++j)
        acc[i][j] = __builtin_amdgcn_mfma_f32_16x16x32_bf16(af[i], bfv[j], acc[i][j], 0, 0, 0);
    __syncthreads();
  }

#pragma unroll
  for (int i = 0; i < AF; ++i)
#pragma unroll
    for (int j = 0; j < BF; ++j)
#pragma unroll
      for (int q = 0; q < 4; ++q) {
        int rr = tm + wr * WM + i * 16 + fg * 4 + q;
        int cc = tn + wc * WN + j * 16 + fr;
        Cz[(size_t)rr * N + cc] = acc[i][j][q];
      }
}

// ---------------- BatchNorm (train mode) ----------------
// reads P split-K partials (stride pstride floats), writes reduced Y and
// per-rowgroup partial sums for stats
__global__ void bn_stats_red_kernel(const float* __restrict__ Yp, float* __restrict__ Yred,
                                    float* __restrict__ psum, float* __restrict__ psq,
                                    int Ncols, int rowsPer, int P, size_t pstride) {
  int c = blockIdx.x * blockDim.x + threadIdx.x;
  int r0 = blockIdx.y * rowsPer;
  float s = 0.f, ss = 0.f;
  for (int r = 0; r < rowsPer; ++r) {
    size_t idx = (size_t)(r0 + r) * Ncols + c;
    float v = Yp[idx];
    for (int p = 1; p < P; ++p) v += Yp[idx + (size_t)p * pstride];
    Yred[idx] = v;
    s += v;
    ss += v * v;
  }
  psum[(size_t)blockIdx.y * Ncols + c] = s;
  psq[(size_t)blockIdx.y * Ncols + c] = ss;
}

__global__ void bn_finalize_kernel(const float* __restrict__ psum, const float* __restrict__ psq,
                                   const float* __restrict__ g, const float* __restrict__ b,
                                   float* __restrict__ scale, float* __restrict__ shift,
                                   int Ncols, int P, float invM) {
  int c = blockIdx.x * blockDim.x + threadIdx.x;
  if (c >= Ncols) return;
  float s = 0.f, ss = 0.f;
  for (int p = 0; p < P; ++p) {
    s += psum[(size_t)p * Ncols + c];
    ss += psq[(size_t)p * Ncols + c];
  }
  float mean = s * invM;
  float var = ss * invM - mean * mean;
  float rstd = rsqrtf(var + 1e-5f);
  float sc = rstd * g[c];
  scale[c] = sc;
  shift[c] = b[c] - mean * sc;
}

__global__ void bn_apply_kernel(const float* __restrict__ Y, const float* __restrict__ scale,
                                const float* __restrict__ shift, unsigned short* __restrict__ X,
                                int NcolsMask, int total) {
  int i = blockIdx.x * blockDim.x + threadIdx.x;
  if (i >= total) return;
  int c = i & NcolsMask;
  float v = Y[i] * scale[c] + shift[c];
  v = fmaxf(v, 0.0f);
  X[i] = f2bf(v);
}

// ---------------- decode ----------------
// Y3 holds KSPLIT=4 partials of (2048 x 96)
__global__ void decode_kernel(const float* __restrict__ Y3, const float* __restrict__ pb,
                              const float* __restrict__ anchors, const int* __restrict__ aid,
                              float* __restrict__ out) {
  int i = blockIdx.x * blockDim.x + threadIdx.x;
  if (i >= 2048 * 94) return;
  int bn = i / 94;
  int ch = i - bn * 94;
  size_t idx = (size_t)bn * 96 + ch;
  float v = Y3[idx] + Y3[idx + 2048 * 96] + Y3[idx + 2 * 2048 * 96] + Y3[idx + 3 * 2048 * 96];
  v += pb[ch];
  float o = v;
  if (ch >= 4 && ch < 22) {
    int q = ch - 4;
    int d = q % 6;   // within-class: 0,1=yx 2,3=lw 4,5=zh
    if (d < 2) {
      float stride_px = (float)(8 << (aid[bn] / 3));
      o = anchors[(size_t)bn * 4 + d] + v * stride_px;
    } else if (d < 4) {
      float cl = fminf(fmaxf(v, -4.0f), 4.0f);
      o = anchors[(size_t)bn * 4 + d] * expf(cl);
    }
  }
  out[i] = o;
}

// ---------------- launch ----------------
extern "C" void kernel_launch(void* const* d_in, const int* in_sizes, int n_in,
                              void* d_out, int out_size, void* d_ws, size_t ws_size,
                              hipStream_t stream) {
  const float* feat_p3   = (const float*)d_in[0];
  const float* feat_p4   = (const float*)d_in[1];
  const float* feat_p5   = (const float*)d_in[2];
  const float* bbox2d    = (const float*)d_in[3];
  const float* anchors   = (const float*)d_in[4];
  const int*   anchor_id = (const int*)d_in[5];
  const float* fc1_w     = (const float*)d_in[6];
  // d_in[7] fc1_b: cancels through train-mode BN (mean subtraction) — unused
  const float* bn1_g     = (const float*)d_in[8];
  const float* bn1_b     = (const float*)d_in[9];
  const float* fc2_w     = (const float*)d_in[10];
  // d_in[11] fc2_b: cancels — unused
  const float* bn2_g     = (const float*)d_in[12];
  const float* bn2_b     = (const float*)d_in[13];
  const float* pred_w    = (const float*)d_in[14];
  const float* pred_b    = (const float*)d_in[15];
  float* out = (float*)d_out;

  const int M = 2048;          // B*N
  const int K1 = 12544;        // 256*7*7
  const int FC = 1024;

  char* ws = (char*)d_ws;
  auto alloc = [&](size_t bytes) -> char* {
    char* p = ws;
    ws += (bytes + 255) & ~(size_t)255;
    return p;
  };
  unsigned short* W1b = (unsigned short*)alloc((size_t)FC * K1 * 2);
  unsigned short* W2b = (unsigned short*)alloc((size_t)FC * FC * 2);
  unsigned short* W3b = (unsigned short*)alloc((size_t)96 * FC * 2);
  unsigned short* X1  = (unsigned short*)alloc((size_t)M * K1 * 2);
  float*          Yp  = (float*)alloc((size_t)4 * M * FC * 4);  // split-K partials (fc1: 4, fc2: 2)
  float*          Yr  = (float*)alloc((size_t)M * FC * 4);      // reduced Y
  unsigned short* X2  = (unsigned short*)alloc((size_t)M * FC * 2);
  unsigned short* X3  = (unsigned short*)alloc((size_t)M * FC * 2);
  float*          Y3  = (float*)alloc((size_t)4 * M * 96 * 4);
  float*          ps  = (float*)alloc((size_t)16 * FC * 4);
  float*          pq  = (float*)alloc((size_t)16 * FC * 4);
  float*          sc1 = (float*)alloc((size_t)FC * 4);
  float*          sh1 = (float*)alloc((size_t)FC * 4);
  float*          sc2 = (float*)alloc((size_t)FC * 4);
  float*          sh2 = (float*)alloc((size_t)FC * 4);

  // weight conversions (must redo each call — no cross-call state allowed)
  {
    size_t n = (size_t)FC * K1;
    cvt_bf16_kernel<<<(unsigned)((n + 255) / 256), 256, 0, stream>>>(fc1_w, W1b, n);
  }
  {
    size_t n = (size_t)FC * FC;
    cvt_bf16_kernel<<<(unsigned)((n + 255) / 256), 256, 0, stream>>>(fc2_w, W2b, n);
  }
  cvt_pad_pred_kernel<<<(96 * 1024) / 256, 256, 0, stream>>>(pred_w, W3b);

  // ROI align -> X1 (2048 x 12544) bf16
  roi_align_v2<<<2048, 256, 0, stream>>>(feat_p3, feat_p4, feat_p5, bbox2d, anchor_id, X1);

  // fc1: X1 (2048x12544) @ W1^T -> Yp (4 partials of 2048x1024)
  gemm_bt_swz<4><<<dim3(M / 128, FC / 128, 4), 256, 0, stream>>>(X1, W1b, Yp, M, FC, K1);

  // BN1: reduce partials + stats, finalize, apply+ReLU -> X2 bf16
  bn_stats_red_kernel<<<dim3(FC / 256, 16), 256, 0, stream>>>(Yp, Yr, ps, pq, FC, M / 16, 4, (size_t)M * FC);
  bn_finalize_kernel<<<FC / 256, 256, 0, stream>>>(ps, pq, bn1_g, bn1_b, sc1, sh1, FC, 16, 1.0f / M);
  bn_apply_kernel<<<(M * FC) / 256, 256, 0, stream>>>(Yr, sc1, sh1, X2, FC - 1, M * FC);

  // fc2: X2 @ W2^T -> Yp (2 partials), reuse Yp
  gemm_bt_swz<2><<<dim3(M / 128, FC / 128, 2), 256, 0, stream>>>(X2, W2b, Yp, M, FC, FC);

  // BN2 + ReLU -> X3 bf16
  bn_stats_red_kernel<<<dim3(FC / 256, 16), 256, 0, stream>>>(Yp, Yr, ps, pq, FC, M / 16, 2, (size_t)M * FC);
  bn_finalize_kernel<<<FC / 256, 256, 0, stream>>>(ps, pq, bn2_g, bn2_b, sc2, sh2, FC, 16, 1.0f / M);
  bn_apply_kernel<<<(M * FC) / 256, 256, 0, stream>>>(Yr, sc2, sh2, X3, FC - 1, M * FC);

  // pred head: X3 @ W3p^T -> Y3 (split-K=4 partials of 2048 x 96)
  gemm_bt_kernel<64, 96, 2, 2, 4><<<dim3(M / 64, 1, 4), 256, 0, stream>>>(X3, W3b, Y3, M, 96, FC);

  // decode -> out (2048 x 94)
  decode_kernel<<<(2048 * 94 + 255) / 256, 256, 0, stream>>>(Y3, pred_b, anchors, anchor_id, out);
}